// Round 1
// baseline (4701.236 us; speedup 1.0000x reference)
//
#include <hip/hip_runtime.h>
#include <math.h>

namespace {
constexpr int kB = 16, kV = 30, kNV = 1501, kNE = 2001, kH = 128, kD = 128,
              kL = 2, kOut = 25, kNT = 100000, kE = 800000, kM = kB * kV;
}

// Pn[n][h] = node_emb[n] . lin_w[h] + lin_b[h]
__global__ void pn_kernel(const float* __restrict__ emb, const float* __restrict__ lw,
                          const float* __restrict__ lb, float* __restrict__ pn) {
  int n = blockIdx.x, h = threadIdx.x;
  __shared__ float row[kD];
  row[h] = emb[(size_t)n * kD + h];
  __syncthreads();
  float acc = lb[h];
#pragma unroll 8
  for (int d = 0; d < kD; d++) acc += row[d] * lw[h * kD + d];
  pn[(size_t)n * kH + h] = acc;
}

// x[i] = Pn[cat_node_ids[i]]
__global__ void xinit_kernel(const float4* __restrict__ pn4, const int* __restrict__ nid,
                             float4* __restrict__ x4) {
  int t = blockIdx.x * blockDim.x + threadIdx.x;
  if (t >= kNT * 32) return;
  int i = t >> 5, c = t & 31;
  x4[(size_t)i * 32 + c] = pn4[(size_t)nid[i] * 32 + c];
}

// u[l][d] = sum_h wr_w[l][h]*lin_w[h][d] ; c[l] = wr_w[l].lin_b + wr_b[l]
__global__ void uc_kernel(const float* __restrict__ wrw, const float* __restrict__ wrb,
                          const float* __restrict__ lw, const float* __restrict__ lb,
                          float* __restrict__ uc) {
  int t = threadIdx.x;  // 256
  int l = t >> 7, d = t & 127;
  float s = 0.f;
  for (int h = 0; h < kH; h++) s += wrw[l * kH + h] * lw[h * kD + d];
  uc[t] = s;
  if (t < kL) {
    float c = wrb[t];
    for (int h = 0; h < kH; h++) c += wrw[t * kH + h] * lb[h];
    uc[256 + t] = c;
  }
}

// wrel[l][r] = sigmoid(edge_emb[r] . u[l] + c[l])
__global__ void wrel_kernel(const float* __restrict__ eemb, const float* __restrict__ uc,
                            float* __restrict__ wrel) {
  int idx = blockIdx.x * blockDim.x + threadIdx.x;
  if (idx >= kL * kNE) return;
  int l = idx / kNE, r = idx % kNE;
  float z = uc[256 + l];
  const float* u = uc + l * 128;
  const float* er = eemb + (size_t)r * kD;
  for (int d = 0; d < kD; d++) z += er[d] * u[d];
  wrel[idx] = 1.f / (1.f + expf(-z));
}

// beta[l][b*V+v] = tanh(vn[b,v,:].beta_w[l] + beta_b[l]) * exp(0.01*(V-v))
__global__ void beta_kernel(const int* __restrict__ vn, const float* __restrict__ bw,
                            const float* __restrict__ bb, float* __restrict__ beta) {
  int blk = blockIdx.x;  // l*kM + r
  int l = blk / kM, r = blk % kM;
  int v = r % kV;
  int lane = threadIdx.x;
  const int* row = vn + (size_t)r * kNV;
  const float* w = bw + (size_t)l * kNV;
  float s = 0.f;
  for (int k = lane; k < kNV; k += 64) s += (float)row[k] * w[k];
  for (int off = 32; off > 0; off >>= 1) s += __shfl_down(s, off, 64);
  if (lane == 0) {
    float lam = expf(0.01f * (float)(kV - v));
    beta[blk] = tanhf(s + bb[l]) * lam;
  }
}

// logits[l][r][n] = vn[r,:].alpha_w[l][n,:] + alpha_b[l][n]  (M=480, N=K=1501)
__global__ void logits_kernel(const int* __restrict__ vn, const float* __restrict__ aw,
                              const float* __restrict__ ab, float* __restrict__ logits) {
  const int l = blockIdx.z;
  const int rowBase = blockIdx.y * 32;
  const int colBase = blockIdx.x * 32;
  const int tx = threadIdx.x, ty = threadIdx.y;  // 16x16
  __shared__ float As[32][33];
  __shared__ float Ws[32][33];
  float acc[2][2] = {{0.f, 0.f}, {0.f, 0.f}};
  const int tid = ty * 16 + tx;
  const float* awl = aw + (size_t)l * kNV * kNV;
  for (int k0 = 0; k0 < kNV; k0 += 32) {
#pragma unroll
    for (int i = 0; i < 4; i++) {
      int idx = tid + i * 256;
      int rr = idx >> 5, cc = idx & 31;
      int gr = rowBase + rr, gk = k0 + cc;
      As[rr][cc] = (gr < kM && gk < kNV) ? (float)vn[(size_t)gr * kNV + gk] : 0.f;
      int gn = colBase + rr;
      Ws[rr][cc] = (gn < kNV && gk < kNV) ? awl[(size_t)gn * kNV + gk] : 0.f;
    }
    __syncthreads();
#pragma unroll
    for (int kk = 0; kk < 32; kk++) {
      float a0 = As[ty * 2][kk], a1 = As[ty * 2 + 1][kk];
      float w0 = Ws[tx * 2][kk], w1 = Ws[tx * 2 + 1][kk];
      acc[0][0] += a0 * w0; acc[0][1] += a0 * w1;
      acc[1][0] += a1 * w0; acc[1][1] += a1 * w1;
    }
    __syncthreads();
  }
  float* Lg = logits + (size_t)l * kM * kNV;
  int r0 = rowBase + ty * 2, n0 = colBase + tx * 2;
#pragma unroll
  for (int i = 0; i < 2; i++)
#pragma unroll
    for (int j = 0; j < 2; j++) {
      int r = r0 + i, n = n0 + j;
      if (r < kM && n < kNV) Lg[(size_t)r * kNV + n] = acc[i][j] + ab[l * kNV + n];
    }
}

// attn[l][b][n] = sum_v softmax_v(logits[l][b,v,n]) * beta[l][b][v]
__global__ void attn_kernel(const float* __restrict__ logits, const float* __restrict__ beta,
                            float* __restrict__ attn) {
  int idx = blockIdx.x * blockDim.x + threadIdx.x;
  if (idx >= kL * kB * kNV) return;
  int n = idx % kNV;
  int lb_ = idx / kNV;  // l*kB + b
  const float* Lg = logits + (size_t)lb_ * kV * kNV + n;
  float z[kV];
  float m = -1e30f;
#pragma unroll
  for (int v = 0; v < kV; v++) {
    z[v] = Lg[(size_t)v * kNV];
    m = fmaxf(m, z[v]);
  }
  float s = 0.f, num = 0.f;
  const float* bet = beta + lb_ * kV;
#pragma unroll
  for (int v = 0; v < kV; v++) {
    float e = expf(z[v] - m);
    s += e;
    num += e * bet[v];
  }
  attn[idx] = num / s;
}

// agg[dst] += relu(x[src] * attn[batch[src], nid[src]] * wrel[eid])
__global__ void edge_kernel(const float* __restrict__ x, const int* __restrict__ src,
                            const int* __restrict__ dst, const int* __restrict__ nid,
                            const int* __restrict__ eid, const int* __restrict__ batch,
                            const float* __restrict__ attn_l, const float* __restrict__ wrel_l,
                            float* __restrict__ agg) {
  long long t = (long long)blockIdx.x * blockDim.x + threadIdx.x;
  int e = (int)(t >> 5);
  if (e >= kE) return;
  int c = ((int)t & 31) << 2;
  int s = src[e];
  float scal = attn_l[(size_t)batch[s] * kNV + nid[s]] * wrel_l[eid[e]];
  float4 xv = *reinterpret_cast<const float4*>(x + (size_t)s * kH + c);
  float* ap = agg + (size_t)dst[e] * kH + c;
  atomicAdd(ap + 0, fmaxf(xv.x * scal, 0.f));
  atomicAdd(ap + 1, fmaxf(xv.y * scal, 0.f));
  atomicAdd(ap + 2, fmaxf(xv.z * scal, 0.f));
  atomicAdd(ap + 3, fmaxf(xv.w * scal, 0.f));
}

// x[node] = relu((agg[node]+x[node]) @ conv_w.T + conv_b)  (in-place safe: per-node block)
__global__ void conv_kernel(const float* __restrict__ agg, const float* __restrict__ w,
                            const float* __restrict__ b, float* __restrict__ x) {
  int node = blockIdx.x, h = threadIdx.x;
  __shared__ float row[kH];
  size_t base = (size_t)node * kH;
  row[h] = agg[base + h] + x[base + h];
  __syncthreads();
  float acc = b[h];
  const float* wr = w + h * kD;
#pragma unroll 8
  for (int d = 0; d < kD; d++) acc += row[d] * wr[d];
  x[base + h] = fmaxf(acc, 0.f);
}

// two-stage segmented mean-pool (sum + count)
__global__ void pool_kernel(const float* __restrict__ x, const int* __restrict__ batch,
                            float* __restrict__ xg, int* __restrict__ cnt) {
  int h = threadIdx.x;  // 128
  int start = blockIdx.x * 256;
  __shared__ float acc[kB][kH];
  __shared__ int scnt[kB];
  for (int b2 = 0; b2 < kB; b2++) acc[b2][h] = 0.f;
  if (h < kB) scnt[h] = 0;
  __syncthreads();
  int end = start + 256;
  if (end > kNT) end = kNT;
  for (int i = start; i < end; i++) {
    int bb = batch[i];
    acc[bb][h] += x[(size_t)i * kH + h];
    if (h == 0) scnt[bb]++;
  }
  __syncthreads();
  for (int b2 = 0; b2 < kB; b2++) atomicAdd(&xg[b2 * kH + h], acc[b2][h]);
  if (h < kB) atomicAdd(&cnt[h], scnt[h]);
}

// node branch: x_node[b] = lin((ehr[b] @ node_emb)/sum(ehr[b]))
__global__ void xnode_kernel(const int* __restrict__ ehr, const float* __restrict__ emb,
                             const float* __restrict__ lw, const float* __restrict__ lb,
                             float* __restrict__ xnode) {
  int b = blockIdx.x, t = threadIdx.x;  // 128
  float acc = 0.f;
  int cnt = 0;
  const int* er = ehr + (size_t)b * kNV;
  for (int n = 0; n < kNV; n++) {
    int e = er[n];
    cnt += e;
    if (e) acc += emb[(size_t)n * kD + t];
  }
  __shared__ float pre[kD];
  pre[t] = acc / (float)cnt;
  __syncthreads();
  float o = lb[t];
  for (int d = 0; d < kD; d++) o += pre[d] * lw[t * kD + d];
  xnode[(size_t)b * kH + t] = o;
}

// out[b][o] = concat(xg[b]/cnt[b], xnode[b]) . mlp_w[o] + mlp_b[o]
__global__ void final_kernel(const float* __restrict__ xg, const int* __restrict__ cnt,
                             const float* __restrict__ xnode, const float* __restrict__ mw,
                             const float* __restrict__ mb, float* __restrict__ out) {
  int idx = blockIdx.x * blockDim.x + threadIdx.x;
  if (idx >= kB * kOut) return;
  int b = idx / kOut, o = idx % kOut;
  float inv = 1.f / (float)cnt[b];
  float acc = mb[o];
  const float* w = mw + (size_t)o * (2 * kH);
  for (int h = 0; h < kH; h++) acc += xg[b * kH + h] * inv * w[h];
  for (int h = 0; h < kH; h++) acc += xnode[b * kH + h] * w[kH + h];
  out[idx] = acc;
}

extern "C" void kernel_launch(void* const* d_in, const int* in_sizes, int n_in,
                              void* d_out, int out_size, void* d_ws, size_t ws_size,
                              hipStream_t stream) {
  const float* node_emb = (const float*)d_in[0];
  const float* edge_emb = (const float*)d_in[1];
  const float* lin_w = (const float*)d_in[2];
  const float* lin_b = (const float*)d_in[3];
  const float* alpha_w = (const float*)d_in[4];
  const float* alpha_b = (const float*)d_in[5];
  const float* beta_w = (const float*)d_in[6];
  const float* beta_b = (const float*)d_in[7];
  const float* wr_w = (const float*)d_in[8];
  const float* wr_b = (const float*)d_in[9];
  const float* conv_w = (const float*)d_in[10];
  const float* conv_b = (const float*)d_in[11];
  const float* mlp_w = (const float*)d_in[12];
  const float* mlp_b = (const float*)d_in[13];
  const int* visit_node = (const int*)d_in[14];
  const int* ehr_nodes = (const int*)d_in[15];
  const int* cat_node_ids = (const int*)d_in[16];
  const int* cat_edge_ids = (const int*)d_in[17];
  const int* edge_index = (const int*)d_in[18];
  const int* batch = (const int*)d_in[19];

  char* ws = (char*)d_ws;
  float* PN = (float*)(ws + 0);            // 768512 B
  float* WREL = (float*)(ws + 768512);     // 16008 B
  float* UC = (float*)(ws + 784640);       // 1032 B
  float* BETA = (float*)(ws + 785920);     // 3840 B
  float* LOGITS = (float*)(ws + 790016);   // 5763840 B
  float* ATTN = (float*)(ws + 6553856);    // 192128 B
  float* XG = (float*)(ws + 6745984);      // 8192 B
  int* CNT = (int*)(ws + 6754176);         // 64 B
  float* XNODE = (float*)(ws + 6754304);   // 8192 B
  float* X = (float*)(ws + 6762496);       // 51200000 B
  float* AGG = (float*)(ws + 57962496);    // 51200000 B

  pn_kernel<<<kNV, kH, 0, stream>>>(node_emb, lin_w, lin_b, PN);
  xinit_kernel<<<(kNT * 32 + 255) / 256, 256, 0, stream>>>((const float4*)PN, cat_node_ids,
                                                           (float4*)X);
  uc_kernel<<<1, 256, 0, stream>>>(wr_w, wr_b, lin_w, lin_b, UC);
  wrel_kernel<<<(kL * kNE + 255) / 256, 256, 0, stream>>>(edge_emb, UC, WREL);
  beta_kernel<<<kL * kM, 64, 0, stream>>>(visit_node, beta_w, beta_b, BETA);
  dim3 lg_grid((kNV + 31) / 32, (kM + 31) / 32, kL);
  logits_kernel<<<lg_grid, dim3(16, 16), 0, stream>>>(visit_node, alpha_w, alpha_b, LOGITS);
  attn_kernel<<<(kL * kB * kNV + 255) / 256, 256, 0, stream>>>(LOGITS, BETA, ATTN);

  const int* src = edge_index;
  const int* dst = edge_index + kE;
  for (int l = 0; l < kL; l++) {
    hipMemsetAsync(AGG, 0, (size_t)kNT * kH * 4, stream);
    edge_kernel<<<(int)(((long long)kE * 32 + 255) / 256), 256, 0, stream>>>(
        X, src, dst, cat_node_ids, cat_edge_ids, batch, ATTN + (size_t)l * kB * kNV,
        WREL + (size_t)l * kNE, AGG);
    conv_kernel<<<kNT, kH, 0, stream>>>(AGG, conv_w + (size_t)l * kH * kD,
                                        conv_b + (size_t)l * kH, X);
  }

  hipMemsetAsync(XG, 0, kB * kH * 4 + 64, stream);
  pool_kernel<<<(kNT + 255) / 256, kH, 0, stream>>>(X, batch, XG, CNT);
  xnode_kernel<<<kB, kH, 0, stream>>>(ehr_nodes, node_emb, lin_w, lin_b, XNODE);
  final_kernel<<<2, 256, 0, stream>>>(XG, CNT, XNODE, mlp_w, mlp_b, (float*)d_out);
}

// Round 2
// 1072.805 us; speedup vs baseline: 4.3822x; 4.3822x over previous
//
#include <hip/hip_runtime.h>
#include <math.h>

namespace {
constexpr int kB = 16, kV = 30, kNV = 1501, kNE = 2001, kH = 128, kD = 128,
              kL = 2, kOut = 25, kNT = 100000, kE = 800000, kM = kB * kV;
constexpr int kNB = (kNT + 255) / 256;  // 391 scan blocks
}

// Pn[n][h] = node_emb[n] . lin_w[h] + lin_b[h]
__global__ void pn_kernel(const float* __restrict__ emb, const float* __restrict__ lw,
                          const float* __restrict__ lb, float* __restrict__ pn) {
  int n = blockIdx.x, h = threadIdx.x;
  __shared__ float row[kD];
  row[h] = emb[(size_t)n * kD + h];
  __syncthreads();
  float acc = lb[h];
#pragma unroll 8
  for (int d = 0; d < kD; d++) acc += row[d] * lw[h * kD + d];
  pn[(size_t)n * kH + h] = acc;
}

// x[i] = Pn[cat_node_ids[i]]
__global__ void xinit_kernel(const float4* __restrict__ pn4, const int* __restrict__ nid,
                             float4* __restrict__ x4) {
  int t = blockIdx.x * blockDim.x + threadIdx.x;
  if (t >= kNT * 32) return;
  int i = t >> 5, c = t & 31;
  x4[(size_t)i * 32 + c] = pn4[(size_t)nid[i] * 32 + c];
}

// u[l][d] = sum_h wr_w[l][h]*lin_w[h][d] ; c[l] = wr_w[l].lin_b + wr_b[l]
__global__ void uc_kernel(const float* __restrict__ wrw, const float* __restrict__ wrb,
                          const float* __restrict__ lw, const float* __restrict__ lb,
                          float* __restrict__ uc) {
  int t = threadIdx.x;  // 256
  int l = t >> 7, d = t & 127;
  float s = 0.f;
  for (int h = 0; h < kH; h++) s += wrw[l * kH + h] * lw[h * kD + d];
  uc[t] = s;
  if (t < kL) {
    float c = wrb[t];
    for (int h = 0; h < kH; h++) c += wrw[t * kH + h] * lb[h];
    uc[256 + t] = c;
  }
}

// wrel[l][r] = sigmoid(edge_emb[r] . u[l] + c[l])
__global__ void wrel_kernel(const float* __restrict__ eemb, const float* __restrict__ uc,
                            float* __restrict__ wrel) {
  int idx = blockIdx.x * blockDim.x + threadIdx.x;
  if (idx >= kL * kNE) return;
  int l = idx / kNE, r = idx % kNE;
  float z = uc[256 + l];
  const float* u = uc + l * 128;
  const float* er = eemb + (size_t)r * kD;
  for (int d = 0; d < kD; d++) z += er[d] * u[d];
  wrel[idx] = 1.f / (1.f + expf(-z));
}

// beta[l][b*V+v] = tanh(vn[b,v,:].beta_w[l] + beta_b[l]) * exp(0.01*(V-v))
__global__ void beta_kernel(const int* __restrict__ vn, const float* __restrict__ bw,
                            const float* __restrict__ bb, float* __restrict__ beta) {
  int blk = blockIdx.x;  // l*kM + r
  int l = blk / kM, r = blk % kM;
  int v = r % kV;
  int lane = threadIdx.x;
  const int* row = vn + (size_t)r * kNV;
  const float* w = bw + (size_t)l * kNV;
  float s = 0.f;
  for (int k = lane; k < kNV; k += 64) s += (float)row[k] * w[k];
  for (int off = 32; off > 0; off >>= 1) s += __shfl_down(s, off, 64);
  if (lane == 0) {
    float lam = expf(0.01f * (float)(kV - v));
    beta[blk] = tanhf(s + bb[l]) * lam;
  }
}

// logits[l][r][n]: tiled GEMM, M-tile 32, N-tile 128, K-chunks of 32, 4x4/thread
__global__ void logits_kernel(const int* __restrict__ vn, const float* __restrict__ aw,
                              const float* __restrict__ ab, float* __restrict__ logits) {
  const int l = blockIdx.z;
  const int rb = blockIdx.y * 32;
  const int nb = blockIdx.x * 128;
  const int tid = threadIdx.x;  // 256
  __shared__ float At[32][36];   // At[k'][r]
  __shared__ float Bc[32][132];  // Bc[k'][n]
  float4 acc0 = {0, 0, 0, 0}, acc1 = {0, 0, 0, 0}, acc2 = {0, 0, 0, 0}, acc3 = {0, 0, 0, 0};
  const float* awl = aw + (size_t)l * kNV * kNV;
  const int h0 = (tid & 31) * 4;  // n offset in tile
  const int r0 = (tid >> 5) * 4;  // r offset in tile
  for (int k0 = 0; k0 < kNV; k0 += 32) {
    __syncthreads();
#pragma unroll
    for (int i = 0; i < 4; ++i) {  // A: 32r x 32k, ints 0/1
      int idx = tid + i * 256;
      int rr = idx >> 5, cc = idx & 31;
      int gk = k0 + cc;
      float v = (gk < kNV) ? (float)vn[(size_t)(rb + rr) * kNV + gk] : 0.f;
      At[cc][rr] = v;
    }
#pragma unroll
    for (int i = 0; i < 16; ++i) {  // B: 32k x 128n from aw[n][k] (scalar: rows odd-length)
      int idx = tid + i * 256;      // 4096
      int nn = idx >> 5, cc = idx & 31;
      int gn = nb + nn, gk = k0 + cc;
      float v = (gn < kNV && gk < kNV) ? awl[(size_t)gn * kNV + gk] : 0.f;
      Bc[cc][nn] = v;
    }
    __syncthreads();
#pragma unroll
    for (int d = 0; d < 32; ++d) {
      float4 a = *(const float4*)&At[d][r0];
      float4 b4 = *(const float4*)&Bc[d][h0];
      acc0.x += a.x * b4.x; acc0.y += a.x * b4.y; acc0.z += a.x * b4.z; acc0.w += a.x * b4.w;
      acc1.x += a.y * b4.x; acc1.y += a.y * b4.y; acc1.z += a.y * b4.z; acc1.w += a.y * b4.w;
      acc2.x += a.z * b4.x; acc2.y += a.z * b4.y; acc2.z += a.z * b4.z; acc2.w += a.z * b4.w;
      acc3.x += a.w * b4.x; acc3.y += a.w * b4.y; acc3.z += a.w * b4.z; acc3.w += a.w * b4.w;
    }
  }
  float* Lg = logits + (size_t)l * kM * kNV;
  const float* abl = ab + (size_t)l * kNV;
  float accs[4][4] = {{acc0.x, acc0.y, acc0.z, acc0.w},
                      {acc1.x, acc1.y, acc1.z, acc1.w},
                      {acc2.x, acc2.y, acc2.z, acc2.w},
                      {acc3.x, acc3.y, acc3.z, acc3.w}};
#pragma unroll
  for (int i = 0; i < 4; ++i) {
    int r = rb + r0 + i;
#pragma unroll
    for (int j = 0; j < 4; ++j) {
      int n = nb + h0 + j;
      if (n < kNV) Lg[(size_t)r * kNV + n] = accs[i][j] + abl[n];
    }
  }
}

// attn[l][b][n] = sum_v softmax_v(logits[l][b,v,n]) * beta[l][b][v]
__global__ void attn_kernel(const float* __restrict__ logits, const float* __restrict__ beta,
                            float* __restrict__ attn) {
  int idx = blockIdx.x * blockDim.x + threadIdx.x;
  if (idx >= kL * kB * kNV) return;
  int n = idx % kNV;
  int lb_ = idx / kNV;  // l*kB + b
  const float* Lg = logits + (size_t)lb_ * kV * kNV + n;
  float z[kV];
  float m = -1e30f;
#pragma unroll
  for (int v = 0; v < kV; v++) {
    z[v] = Lg[(size_t)v * kNV];
    m = fmaxf(m, z[v]);
  }
  float s = 0.f, num = 0.f;
  const float* bet = beta + lb_ * kV;
#pragma unroll
  for (int v = 0; v < kV; v++) {
    float e = expf(z[v] - m);
    s += e;
    num += e * bet[v];
  }
  attn[idx] = num / s;
}

// ---- CSR build ----
__global__ void hist_kernel(const int* __restrict__ dst, int* __restrict__ deg) {
  int e = blockIdx.x * blockDim.x + threadIdx.x;
  if (e >= kE) return;
  atomicAdd(&deg[dst[e]], 1);
}

__global__ void scan1_kernel(const int* __restrict__ deg, int* __restrict__ off,
                             int* __restrict__ part) {
  int t = threadIdx.x, i = blockIdx.x * 256 + t;
  int v = (i < kNT) ? deg[i] : 0;
  __shared__ int sm[256];
  sm[t] = v;
  __syncthreads();
  for (int o = 1; o < 256; o <<= 1) {
    int x = (t >= o) ? sm[t - o] : 0;
    __syncthreads();
    sm[t] += x;
    __syncthreads();
  }
  if (i < kNT) off[i] = sm[t] - v;
  if (t == 255) part[blockIdx.x] = sm[255];
}

__global__ void scan2_kernel(int* __restrict__ part) {
  int t = threadIdx.x;  // 512
  int v = (t < kNB) ? part[t] : 0;
  __shared__ int sm[512];
  sm[t] = v;
  __syncthreads();
  for (int o = 1; o < 512; o <<= 1) {
    int x = (t >= o) ? sm[t - o] : 0;
    __syncthreads();
    sm[t] += x;
    __syncthreads();
  }
  if (t < kNB) part[t] = sm[t] - v;
}

__global__ void scan3_kernel(int* __restrict__ off, const int* __restrict__ part,
                             int* __restrict__ cursor) {
  int i = blockIdx.x * 256 + threadIdx.x;
  if (i >= kNT) return;
  int o = off[i] + part[blockIdx.x];
  off[i] = o;
  cursor[i] = o;
}

// scatter edges into CSR slots; precompute per-edge scalars for both layers
__global__ void scatter_kernel(const int* __restrict__ ei, const int* __restrict__ nid,
                               const int* __restrict__ eid, const int* __restrict__ batch,
                               const float* __restrict__ attn, const float* __restrict__ wrel,
                               int* __restrict__ cursor, int* __restrict__ csrc,
                               float* __restrict__ cs0, float* __restrict__ cs1) {
  int e = blockIdx.x * blockDim.x + threadIdx.x;
  if (e >= kE) return;
  int s = ei[e], d = ei[kE + e];
  int b = batch[s], n = nid[s], r = eid[e];
  float a0 = attn[(size_t)b * kNV + n];
  float a1 = attn[(size_t)kB * kNV + b * kNV + n];
  float w0 = wrel[r], w1 = wrel[kNE + r];
  int pos = atomicAdd(&cursor[d], 1);
  csrc[pos] = s;
  cs0[pos] = a0 * w0;
  cs1[pos] = a1 * w1;
}

// rows[n] = x[n] + sum_{edges->n} relu(x[src]*scal)   (wave per node, float2/lane)
__global__ void gather_kernel(const float* __restrict__ x, const int* __restrict__ csrc,
                              const float* __restrict__ cscal, const int* __restrict__ off,
                              const int* __restrict__ endv, float* __restrict__ rows) {
  int node = blockIdx.x * 4 + (threadIdx.x >> 6);
  int lane = threadIdx.x & 63;
  const float2* x2 = (const float2*)x;
  float2 acc = x2[(size_t)node * 64 + lane];
  int j1 = endv[node];
  for (int j = off[node]; j < j1; ++j) {
    int s = csrc[j];
    float sc = cscal[j];
    float2 xv = x2[(size_t)s * 64 + lane];
    acc.x += fmaxf(xv.x * sc, 0.f);
    acc.y += fmaxf(xv.y * sc, 0.f);
  }
  ((float2*)rows)[(size_t)node * 64 + lane] = acc;
}

// x_out[n][h] = relu(rows[n] . w[h] + bias[h]); 32 nodes/block, K-chunks of 32, 4x4/thread
__global__ void conv_kernel(const float* __restrict__ rows, const float* __restrict__ w,
                            const float* __restrict__ bias, float* __restrict__ xout) {
  const int nb = blockIdx.x * 32;
  const int tid = threadIdx.x;  // 256
  __shared__ float rT[128][36];   // rT[d][n]
  __shared__ float Wc[32][132];   // Wc[d'][h]
  float4 acc0 = {0, 0, 0, 0}, acc1 = {0, 0, 0, 0}, acc2 = {0, 0, 0, 0}, acc3 = {0, 0, 0, 0};
#pragma unroll
  for (int i = 0; i < 4; ++i) {  // stage rows tile transposed (float4, aligned)
    int fi = tid + i * 256;      // 1024 float4 = 4096 floats
    int n = fi >> 5, d0 = (fi & 31) * 4;
    float4 v = *(const float4*)(rows + (size_t)(nb + n) * kH + d0);
    rT[d0 + 0][n] = v.x;
    rT[d0 + 1][n] = v.y;
    rT[d0 + 2][n] = v.z;
    rT[d0 + 3][n] = v.w;
  }
  const int h0 = (tid & 31) * 4;
  const int n0 = (tid >> 5) * 4;
  for (int kc = 0; kc < 4; ++kc) {
    __syncthreads();
#pragma unroll
    for (int i = 0; i < 4; ++i) {  // stage W chunk: Wc[d'][h] = w[h][kc*32+d']
      int fi = tid + i * 256;      // 1024 float4
      int h = fi >> 3, c0 = (fi & 7) * 4;
      float4 v = *(const float4*)(w + (size_t)h * kD + kc * 32 + c0);
      Wc[c0 + 0][h] = v.x;
      Wc[c0 + 1][h] = v.y;
      Wc[c0 + 2][h] = v.z;
      Wc[c0 + 3][h] = v.w;
    }
    __syncthreads();
#pragma unroll
    for (int d = 0; d < 32; ++d) {
      float4 a = *(const float4*)&rT[kc * 32 + d][n0];
      float4 b4 = *(const float4*)&Wc[d][h0];
      acc0.x += a.x * b4.x; acc0.y += a.x * b4.y; acc0.z += a.x * b4.z; acc0.w += a.x * b4.w;
      acc1.x += a.y * b4.x; acc1.y += a.y * b4.y; acc1.z += a.y * b4.z; acc1.w += a.y * b4.w;
      acc2.x += a.z * b4.x; acc2.y += a.z * b4.y; acc2.z += a.z * b4.z; acc2.w += a.z * b4.w;
      acc3.x += a.w * b4.x; acc3.y += a.w * b4.y; acc3.z += a.w * b4.z; acc3.w += a.w * b4.w;
    }
  }
  float4 bv = *(const float4*)(bias + h0);
  float4 o0, o1, o2, o3;
  o0.x = fmaxf(acc0.x + bv.x, 0.f); o0.y = fmaxf(acc0.y + bv.y, 0.f);
  o0.z = fmaxf(acc0.z + bv.z, 0.f); o0.w = fmaxf(acc0.w + bv.w, 0.f);
  o1.x = fmaxf(acc1.x + bv.x, 0.f); o1.y = fmaxf(acc1.y + bv.y, 0.f);
  o1.z = fmaxf(acc1.z + bv.z, 0.f); o1.w = fmaxf(acc1.w + bv.w, 0.f);
  o2.x = fmaxf(acc2.x + bv.x, 0.f); o2.y = fmaxf(acc2.y + bv.y, 0.f);
  o2.z = fmaxf(acc2.z + bv.z, 0.f); o2.w = fmaxf(acc2.w + bv.w, 0.f);
  o3.x = fmaxf(acc3.x + bv.x, 0.f); o3.y = fmaxf(acc3.y + bv.y, 0.f);
  o3.z = fmaxf(acc3.z + bv.z, 0.f); o3.w = fmaxf(acc3.w + bv.w, 0.f);
  *(float4*)(xout + (size_t)(nb + n0 + 0) * kH + h0) = o0;
  *(float4*)(xout + (size_t)(nb + n0 + 1) * kH + h0) = o1;
  *(float4*)(xout + (size_t)(nb + n0 + 2) * kH + h0) = o2;
  *(float4*)(xout + (size_t)(nb + n0 + 3) * kH + h0) = o3;
}

// two-stage segmented mean-pool (sum + count)
__global__ void pool_kernel(const float* __restrict__ x, const int* __restrict__ batch,
                            float* __restrict__ xg, int* __restrict__ cnt) {
  int h = threadIdx.x;  // 128
  int start = blockIdx.x * 256;
  __shared__ float acc[kB][kH];
  __shared__ int scnt[kB];
  for (int b2 = 0; b2 < kB; b2++) acc[b2][h] = 0.f;
  if (h < kB) scnt[h] = 0;
  __syncthreads();
  int end = start + 256;
  if (end > kNT) end = kNT;
  for (int i = start; i < end; i++) {
    int bb = batch[i];
    acc[bb][h] += x[(size_t)i * kH + h];
    if (h == 0) scnt[bb]++;
  }
  __syncthreads();
  for (int b2 = 0; b2 < kB; b2++) atomicAdd(&xg[b2 * kH + h], acc[b2][h]);
  if (h < kB) atomicAdd(&cnt[h], scnt[h]);
}

// node branch: x_node[b] = lin((ehr[b] @ node_emb)/sum(ehr[b]))
__global__ void xnode_kernel(const int* __restrict__ ehr, const float* __restrict__ emb,
                             const float* __restrict__ lw, const float* __restrict__ lb,
                             float* __restrict__ xnode) {
  int b = blockIdx.x, t = threadIdx.x;  // 128
  float acc = 0.f;
  int cnt = 0;
  const int* er = ehr + (size_t)b * kNV;
  for (int n = 0; n < kNV; n++) {
    int e = er[n];
    cnt += e;
    if (e) acc += emb[(size_t)n * kD + t];
  }
  __shared__ float pre[kD];
  pre[t] = acc / (float)cnt;
  __syncthreads();
  float o = lb[t];
  for (int d = 0; d < kD; d++) o += pre[d] * lw[t * kD + d];
  xnode[(size_t)b * kH + t] = o;
}

// out[b][o] = concat(xg[b]/cnt[b], xnode[b]) . mlp_w[o] + mlp_b[o]
__global__ void final_kernel(const float* __restrict__ xg, const int* __restrict__ cnt,
                             const float* __restrict__ xnode, const float* __restrict__ mw,
                             const float* __restrict__ mb, float* __restrict__ out) {
  int idx = blockIdx.x * blockDim.x + threadIdx.x;
  if (idx >= kB * kOut) return;
  int b = idx / kOut, o = idx % kOut;
  float inv = 1.f / (float)cnt[b];
  float acc = mb[o];
  const float* w = mw + (size_t)o * (2 * kH);
  for (int h = 0; h < kH; h++) acc += xg[b * kH + h] * inv * w[h];
  for (int h = 0; h < kH; h++) acc += xnode[b * kH + h] * w[kH + h];
  out[idx] = acc;
}

extern "C" void kernel_launch(void* const* d_in, const int* in_sizes, int n_in,
                              void* d_out, int out_size, void* d_ws, size_t ws_size,
                              hipStream_t stream) {
  const float* node_emb = (const float*)d_in[0];
  const float* edge_emb = (const float*)d_in[1];
  const float* lin_w = (const float*)d_in[2];
  const float* lin_b = (const float*)d_in[3];
  const float* alpha_w = (const float*)d_in[4];
  const float* alpha_b = (const float*)d_in[5];
  const float* beta_w = (const float*)d_in[6];
  const float* beta_b = (const float*)d_in[7];
  const float* wr_w = (const float*)d_in[8];
  const float* wr_b = (const float*)d_in[9];
  const float* conv_w = (const float*)d_in[10];
  const float* conv_b = (const float*)d_in[11];
  const float* mlp_w = (const float*)d_in[12];
  const float* mlp_b = (const float*)d_in[13];
  const int* visit_node = (const int*)d_in[14];
  const int* ehr_nodes = (const int*)d_in[15];
  const int* cat_node_ids = (const int*)d_in[16];
  const int* cat_edge_ids = (const int*)d_in[17];
  const int* edge_index = (const int*)d_in[18];
  const int* batch = (const int*)d_in[19];

  char* ws = (char*)d_ws;
  float* X = (float*)(ws);                            // 51,200,000
  float* ROWS = (float*)(ws + 51200000);              // 51,200,000
  float* PN = ROWS;                                   // alias (dead before ROWS used)
  float* LOGITS = (float*)(ws + 51200000 + 786432);   // alias in ROWS, 5,763,840
  float* ATTN = (float*)(ws + 102400000);             // 192,128
  float* BETA = (float*)(ws + 102592256);             // 3,840
  float* UC = (float*)(ws + 102596352);               // 1,032
  float* WREL = (float*)(ws + 102597632);             // 16,008
  int* OFF = (int*)(ws + 102613760);                  // 400,004
  int* CURSOR = (int*)(ws + 103014016);               // 400,000 (also DEG)
  int* PART = (int*)(ws + 103414016);                 // 2,048
  int* CSRS = (int*)(ws + 103416064);                 // 3,200,000
  float* CS0 = (float*)(ws + 106616064);              // 3,200,000
  float* CS1 = (float*)(ws + 109816064);              // 3,200,000
  float* XG = (float*)(ws + 113016064);               // 8,192
  int* CNT = (int*)(ws + 113024256);                  // 64 (contiguous after XG)
  float* XNODE = (float*)(ws + 113024320);            // 8,192

  pn_kernel<<<kNV, kH, 0, stream>>>(node_emb, lin_w, lin_b, PN);
  xinit_kernel<<<(kNT * 32 + 255) / 256, 256, 0, stream>>>((const float4*)PN, cat_node_ids,
                                                           (float4*)X);
  uc_kernel<<<1, 256, 0, stream>>>(wr_w, wr_b, lin_w, lin_b, UC);
  wrel_kernel<<<(kL * kNE + 255) / 256, 256, 0, stream>>>(edge_emb, UC, WREL);
  beta_kernel<<<kL * kM, 64, 0, stream>>>(visit_node, beta_w, beta_b, BETA);
  logits_kernel<<<dim3((kNV + 127) / 128, kM / 32, kL), 256, 0, stream>>>(visit_node, alpha_w,
                                                                          alpha_b, LOGITS);
  attn_kernel<<<(kL * kB * kNV + 255) / 256, 256, 0, stream>>>(LOGITS, BETA, ATTN);

  const int* dst = edge_index + kE;
  hipMemsetAsync(CURSOR, 0, kNT * 4, stream);
  hist_kernel<<<(kE + 255) / 256, 256, 0, stream>>>(dst, CURSOR);
  scan1_kernel<<<kNB, 256, 0, stream>>>(CURSOR, OFF, PART);
  scan2_kernel<<<1, 512, 0, stream>>>(PART);
  scan3_kernel<<<kNB, 256, 0, stream>>>(OFF, PART, CURSOR);
  scatter_kernel<<<(kE + 255) / 256, 256, 0, stream>>>(edge_index, cat_node_ids, cat_edge_ids,
                                                       batch, ATTN, WREL, CURSOR, CSRS, CS0, CS1);

  for (int l = 0; l < kL; l++) {
    gather_kernel<<<kNT / 4, 256, 0, stream>>>(X, CSRS, (l ? CS1 : CS0), OFF, CURSOR, ROWS);
    conv_kernel<<<kNT / 32, 256, 0, stream>>>(ROWS, conv_w + (size_t)l * kH * kD,
                                              conv_b + (size_t)l * kH, X);
  }

  hipMemsetAsync(XG, 0, kB * kH * 4 + 64, stream);
  pool_kernel<<<(kNT + 255) / 256, kH, 0, stream>>>(X, batch, XG, CNT);
  xnode_kernel<<<kB, kH, 0, stream>>>(ehr_nodes, node_emb, lin_w, lin_b, XNODE);
  final_kernel<<<2, 256, 0, stream>>>(XG, CNT, XNODE, mlp_w, mlp_b, (float*)d_out);
}

// Round 3
// 908.797 us; speedup vs baseline: 5.1730x; 1.1805x over previous
//
#include <hip/hip_runtime.h>
#include <math.h>

namespace {
constexpr int kB = 16, kV = 30, kNV = 1501, kNE = 2001, kH = 128, kD = 128,
              kL = 2, kOut = 25, kNT = 100000, kE = 800000, kM = kB * kV;
constexpr int kNB = (kNT + 255) / 256;  // 391 scan blocks
constexpr int kKS = 3;                  // split-K factor for logits
constexpr int kKCH = 501;               // ceil(1501/3)
}

// Pn[n][h] = node_emb[n] . lin_w[h] + lin_b[h]
__global__ void pn_kernel(const float* __restrict__ emb, const float* __restrict__ lw,
                          const float* __restrict__ lb, float* __restrict__ pn) {
  int n = blockIdx.x, h = threadIdx.x;
  __shared__ float row[kD];
  row[h] = emb[(size_t)n * kD + h];
  __syncthreads();
  float acc = lb[h];
#pragma unroll 8
  for (int d = 0; d < kD; d++) acc += row[d] * lw[h * kD + d];
  pn[(size_t)n * kH + h] = acc;
}

// x[i] = Pn[cat_node_ids[i]]
__global__ void xinit_kernel(const float4* __restrict__ pn4, const int* __restrict__ nid,
                             float4* __restrict__ x4) {
  int t = blockIdx.x * blockDim.x + threadIdx.x;
  if (t >= kNT * 32) return;
  int i = t >> 5, c = t & 31;
  x4[(size_t)i * 32 + c] = pn4[(size_t)nid[i] * 32 + c];
}

// u[l][d] = sum_h wr_w[l][h]*lin_w[h][d] ; c[l] = wr_w[l].lin_b + wr_b[l]
__global__ void uc_kernel(const float* __restrict__ wrw, const float* __restrict__ wrb,
                          const float* __restrict__ lw, const float* __restrict__ lb,
                          float* __restrict__ uc) {
  int t = threadIdx.x;  // 256
  int l = t >> 7, d = t & 127;
  float s = 0.f;
  for (int h = 0; h < kH; h++) s += wrw[l * kH + h] * lw[h * kD + d];
  uc[t] = s;
  if (t < kL) {
    float c = wrb[t];
    for (int h = 0; h < kH; h++) c += wrw[t * kH + h] * lb[h];
    uc[256 + t] = c;
  }
}

// wrel[l][r] = sigmoid(edge_emb[r] . u[l] + c[l])
__global__ void wrel_kernel(const float* __restrict__ eemb, const float* __restrict__ uc,
                            float* __restrict__ wrel) {
  int idx = blockIdx.x * blockDim.x + threadIdx.x;
  if (idx >= kL * kNE) return;
  int l = idx / kNE, r = idx % kNE;
  float z = uc[256 + l];
  const float* u = uc + l * 128;
  const float* er = eemb + (size_t)r * kD;
  for (int d = 0; d < kD; d++) z += er[d] * u[d];
  wrel[idx] = 1.f / (1.f + expf(-z));
}

// beta[l][b*V+v] = tanh(vn[b,v,:].beta_w[l] + beta_b[l]) * exp(0.01*(V-v))
__global__ void beta_kernel(const int* __restrict__ vn, const float* __restrict__ bw,
                            const float* __restrict__ bb, float* __restrict__ beta) {
  int blk = blockIdx.x;  // l*kM + r
  int l = blk / kM, r = blk % kM;
  int v = r % kV;
  int lane = threadIdx.x;
  const int* row = vn + (size_t)r * kNV;
  const float* w = bw + (size_t)l * kNV;
  float s = 0.f;
  for (int k = lane; k < kNV; k += 64) s += (float)row[k] * w[k];
  for (int off = 32; off > 0; off >>= 1) s += __shfl_down(s, off, 64);
  if (lane == 0) {
    float lam = expf(0.01f * (float)(kV - v));
    beta[blk] = tanhf(s + bb[l]) * lam;
  }
}

// Partial logits: part[z][r][n] = sum_{k in chunk ks} vn[r][k]*aw[l][n][k], z=l*kKS+ks
// 64x64 tile, 4x4 per thread, K-step 32. Grid (24, 8, kL*kKS) = 1152 blocks.
__global__ void logits_kernel(const int* __restrict__ vn, const float* __restrict__ aw,
                              float* __restrict__ part) {
  const int z = blockIdx.z;
  const int l = z / kKS, ks = z % kKS;
  const int rb = blockIdx.y * 64;
  const int nb = blockIdx.x * 64;
  const int tid = threadIdx.x;  // 256
  const int kbeg = ks * kKCH;
  const int kend = min(kbeg + kKCH, kNV);
  __shared__ float As[32][68];  // As[k'][m]
  __shared__ float Bs[32][68];  // Bs[k'][n]
  const float* awl = aw + (size_t)l * kNV * kNV;
  const int tx = tid & 15, ty = tid >> 4;
  const int m0 = ty * 4, n0 = tx * 4;
  float acc[4][4] = {};
  for (int k0 = kbeg; k0 < kend; k0 += 32) {
    __syncthreads();
#pragma unroll
    for (int i = 0; i < 8; ++i) {  // A: 64 m x 32 k (transposed store)
      int idx = tid + i * 256;
      int rr = idx >> 5, cc = idx & 31;
      int gr = rb + rr, gk = k0 + cc;
      As[cc][rr] = (gr < kM && gk < kend) ? (float)vn[(size_t)gr * kNV + gk] : 0.f;
    }
#pragma unroll
    for (int i = 0; i < 8; ++i) {  // B: 64 n x 32 k (transposed store)
      int idx = tid + i * 256;
      int nn = idx >> 5, cc = idx & 31;
      int gn = nb + nn, gk = k0 + cc;
      Bs[cc][nn] = (gn < kNV && gk < kend) ? awl[(size_t)gn * kNV + gk] : 0.f;
    }
    __syncthreads();
#pragma unroll
    for (int d = 0; d < 32; ++d) {
      float4 a = *(const float4*)&As[d][m0];
      float4 b4 = *(const float4*)&Bs[d][n0];
      acc[0][0] += a.x * b4.x; acc[0][1] += a.x * b4.y; acc[0][2] += a.x * b4.z; acc[0][3] += a.x * b4.w;
      acc[1][0] += a.y * b4.x; acc[1][1] += a.y * b4.y; acc[1][2] += a.y * b4.z; acc[1][3] += a.y * b4.w;
      acc[2][0] += a.z * b4.x; acc[2][1] += a.z * b4.y; acc[2][2] += a.z * b4.z; acc[2][3] += a.z * b4.w;
      acc[3][0] += a.w * b4.x; acc[3][1] += a.w * b4.y; acc[3][2] += a.w * b4.z; acc[3][3] += a.w * b4.w;
    }
  }
  float* P = part + (size_t)z * kM * kNV;
#pragma unroll
  for (int i = 0; i < 4; ++i) {
    int r = rb + m0 + i;
    if (r >= kM) break;
#pragma unroll
    for (int j = 0; j < 4; ++j) {
      int n = nb + n0 + j;
      if (n < kNV) P[(size_t)r * kNV + n] = acc[i][j];
    }
  }
}

// attn[l][b][n] = sum_v softmax_v(sum_ks part + bias) * beta[l][b][v]
__global__ void attn_kernel(const float* __restrict__ part, const float* __restrict__ beta,
                            const float* __restrict__ ab, float* __restrict__ attn) {
  int idx = blockIdx.x * blockDim.x + threadIdx.x;
  if (idx >= kL * kB * kNV) return;
  int n = idx % kNV;
  int lb_ = idx / kNV;  // l*kB + b
  int l = lb_ / kB, b = lb_ % kB;
  size_t o = (size_t)(b * kV) * kNV + n;
  const float* P0 = part + (size_t)(l * kKS + 0) * kM * kNV + o;
  const float* P1 = part + (size_t)(l * kKS + 1) * kM * kNV + o;
  const float* P2 = part + (size_t)(l * kKS + 2) * kM * kNV + o;
  float bias = ab[l * kNV + n];
  float z[kV];
  float m = -1e30f;
#pragma unroll
  for (int v = 0; v < kV; v++) {
    z[v] = P0[(size_t)v * kNV] + P1[(size_t)v * kNV] + P2[(size_t)v * kNV] + bias;
    m = fmaxf(m, z[v]);
  }
  float s = 0.f, num = 0.f;
  const float* bet = beta + lb_ * kV;
#pragma unroll
  for (int v = 0; v < kV; v++) {
    float e = expf(z[v] - m);
    s += e;
    num += e * bet[v];
  }
  attn[idx] = num / s;
}

// ---- CSR build ----
__global__ void hist_kernel(const int* __restrict__ dst, int* __restrict__ deg) {
  int e = blockIdx.x * blockDim.x + threadIdx.x;
  if (e >= kE) return;
  atomicAdd(&deg[dst[e]], 1);
}

__global__ void scan1_kernel(const int* __restrict__ deg, int* __restrict__ off,
                             int* __restrict__ part) {
  int t = threadIdx.x, i = blockIdx.x * 256 + t;
  int v = (i < kNT) ? deg[i] : 0;
  __shared__ int sm[256];
  sm[t] = v;
  __syncthreads();
  for (int o = 1; o < 256; o <<= 1) {
    int x = (t >= o) ? sm[t - o] : 0;
    __syncthreads();
    sm[t] += x;
    __syncthreads();
  }
  if (i < kNT) off[i] = sm[t] - v;
  if (t == 255) part[blockIdx.x] = sm[255];
}

__global__ void scan2_kernel(int* __restrict__ part) {
  int t = threadIdx.x;  // 512
  int v = (t < kNB) ? part[t] : 0;
  __shared__ int sm[512];
  sm[t] = v;
  __syncthreads();
  for (int o = 1; o < 512; o <<= 1) {
    int x = (t >= o) ? sm[t - o] : 0;
    __syncthreads();
    sm[t] += x;
    __syncthreads();
  }
  if (t < kNB) part[t] = sm[t] - v;
}

__global__ void scan3_kernel(int* __restrict__ off, const int* __restrict__ part,
                             int* __restrict__ cursor) {
  int i = blockIdx.x * 256 + threadIdx.x;
  if (i >= kNT) return;
  int o = off[i] + part[blockIdx.x];
  off[i] = o;
  cursor[i] = o;
}

// scatter edges into CSR slots; precompute per-edge scalars for both layers
__global__ void scatter_kernel(const int* __restrict__ ei, const int* __restrict__ nid,
                               const int* __restrict__ eid, const int* __restrict__ batch,
                               const float* __restrict__ attn, const float* __restrict__ wrel,
                               int* __restrict__ cursor, int* __restrict__ csrc,
                               float* __restrict__ cs0, float* __restrict__ cs1) {
  int e = blockIdx.x * blockDim.x + threadIdx.x;
  if (e >= kE) return;
  int s = ei[e], d = ei[kE + e];
  int b = batch[s], n = nid[s], r = eid[e];
  float a0 = attn[(size_t)b * kNV + n];
  float a1 = attn[(size_t)kB * kNV + b * kNV + n];
  float w0 = wrel[r], w1 = wrel[kNE + r];
  int pos = atomicAdd(&cursor[d], 1);
  csrc[pos] = s;
  cs0[pos] = a0 * w0;
  cs1[pos] = a1 * w1;
}

// rows[n] = x[n] + sum_{edges->n} relu(x[src]*scal)
// 2 nodes per wave, float4 per lane (32 lanes/row), 32-edge register prefetch.
__global__ void gather_kernel(const float* __restrict__ x, const int* __restrict__ csrc,
                              const float* __restrict__ cscal, const int* __restrict__ off,
                              const int* __restrict__ endv, float* __restrict__ rows) {
  int wid = (blockIdx.x * blockDim.x + threadIdx.x) >> 6;
  int lane = threadIdx.x & 63;
  int sub = lane >> 5, sl = lane & 31;
  int node = wid * 2 + sub;
  if (node >= kNT) return;
  const float4* x4 = (const float4*)x;
  float4 acc = x4[(size_t)node * 32 + sl];
  int j0 = off[node], j1 = endv[node];
  for (int base = j0; base < j1; base += 32) {
    int n = j1 - base;
    if (n > 32) n = 32;
    int sidx = 0;
    float ssc = 0.f;
    if (sl < n) {
      sidx = csrc[base + sl];
      ssc = cscal[base + sl];
    }
    for (int t = 0; t < n; ++t) {
      int s = __shfl(sidx, sub * 32 + t, 64);
      float sc = __shfl(ssc, sub * 32 + t, 64);
      float4 xv = x4[(size_t)s * 32 + sl];
      acc.x += fmaxf(xv.x * sc, 0.f);
      acc.y += fmaxf(xv.y * sc, 0.f);
      acc.z += fmaxf(xv.z * sc, 0.f);
      acc.w += fmaxf(xv.w * sc, 0.f);
    }
  }
  ((float4*)rows)[(size_t)node * 32 + sl] = acc;
}

// x_out[n][h] = relu(rows[n] . w[h] + bias[h]); 32 nodes/block, K-chunks of 32, 4x4/thread
__global__ void conv_kernel(const float* __restrict__ rows, const float* __restrict__ w,
                            const float* __restrict__ bias, float* __restrict__ xout) {
  const int nb = blockIdx.x * 32;
  const int tid = threadIdx.x;  // 256
  __shared__ float rT[128][36];   // rT[d][n]
  __shared__ float Wc[32][132];   // Wc[d'][h]
  float4 acc0 = {0, 0, 0, 0}, acc1 = {0, 0, 0, 0}, acc2 = {0, 0, 0, 0}, acc3 = {0, 0, 0, 0};
#pragma unroll
  for (int i = 0; i < 4; ++i) {
    int fi = tid + i * 256;
    int n = fi >> 5, d0 = (fi & 31) * 4;
    float4 v = *(const float4*)(rows + (size_t)(nb + n) * kH + d0);
    rT[d0 + 0][n] = v.x;
    rT[d0 + 1][n] = v.y;
    rT[d0 + 2][n] = v.z;
    rT[d0 + 3][n] = v.w;
  }
  const int h0 = (tid & 31) * 4;
  const int n0 = (tid >> 5) * 4;
  for (int kc = 0; kc < 4; ++kc) {
    __syncthreads();
#pragma unroll
    for (int i = 0; i < 4; ++i) {
      int fi = tid + i * 256;
      int h = fi >> 3, c0 = (fi & 7) * 4;
      float4 v = *(const float4*)(w + (size_t)h * kD + kc * 32 + c0);
      Wc[c0 + 0][h] = v.x;
      Wc[c0 + 1][h] = v.y;
      Wc[c0 + 2][h] = v.z;
      Wc[c0 + 3][h] = v.w;
    }
    __syncthreads();
#pragma unroll
    for (int d = 0; d < 32; ++d) {
      float4 a = *(const float4*)&rT[kc * 32 + d][n0];
      float4 b4 = *(const float4*)&Wc[d][h0];
      acc0.x += a.x * b4.x; acc0.y += a.x * b4.y; acc0.z += a.x * b4.z; acc0.w += a.x * b4.w;
      acc1.x += a.y * b4.x; acc1.y += a.y * b4.y; acc1.z += a.y * b4.z; acc1.w += a.y * b4.w;
      acc2.x += a.z * b4.x; acc2.y += a.z * b4.y; acc2.z += a.z * b4.z; acc2.w += a.z * b4.w;
      acc3.x += a.w * b4.x; acc3.y += a.w * b4.y; acc3.z += a.w * b4.z; acc3.w += a.w * b4.w;
    }
  }
  float4 bv = *(const float4*)(bias + h0);
  float4 o0, o1, o2, o3;
  o0.x = fmaxf(acc0.x + bv.x, 0.f); o0.y = fmaxf(acc0.y + bv.y, 0.f);
  o0.z = fmaxf(acc0.z + bv.z, 0.f); o0.w = fmaxf(acc0.w + bv.w, 0.f);
  o1.x = fmaxf(acc1.x + bv.x, 0.f); o1.y = fmaxf(acc1.y + bv.y, 0.f);
  o1.z = fmaxf(acc1.z + bv.z, 0.f); o1.w = fmaxf(acc1.w + bv.w, 0.f);
  o2.x = fmaxf(acc2.x + bv.x, 0.f); o2.y = fmaxf(acc2.y + bv.y, 0.f);
  o2.z = fmaxf(acc2.z + bv.z, 0.f); o2.w = fmaxf(acc2.w + bv.w, 0.f);
  o3.x = fmaxf(acc3.x + bv.x, 0.f); o3.y = fmaxf(acc3.y + bv.y, 0.f);
  o3.z = fmaxf(acc3.z + bv.z, 0.f); o3.w = fmaxf(acc3.w + bv.w, 0.f);
  *(float4*)(xout + (size_t)(nb + n0 + 0) * kH + h0) = o0;
  *(float4*)(xout + (size_t)(nb + n0 + 1) * kH + h0) = o1;
  *(float4*)(xout + (size_t)(nb + n0 + 2) * kH + h0) = o2;
  *(float4*)(xout + (size_t)(nb + n0 + 3) * kH + h0) = o3;
}

// two-stage segmented mean-pool (sum + count)
__global__ void pool_kernel(const float* __restrict__ x, const int* __restrict__ batch,
                            float* __restrict__ xg, int* __restrict__ cnt) {
  int h = threadIdx.x;  // 128
  int start = blockIdx.x * 256;
  __shared__ float acc[kB][kH];
  __shared__ int scnt[kB];
  for (int b2 = 0; b2 < kB; b2++) acc[b2][h] = 0.f;
  if (h < kB) scnt[h] = 0;
  __syncthreads();
  int end = start + 256;
  if (end > kNT) end = kNT;
  for (int i = start; i < end; i++) {
    int bb = batch[i];
    acc[bb][h] += x[(size_t)i * kH + h];
    if (h == 0) scnt[bb]++;
  }
  __syncthreads();
  for (int b2 = 0; b2 < kB; b2++) atomicAdd(&xg[b2 * kH + h], acc[b2][h]);
  if (h < kB) atomicAdd(&cnt[h], scnt[h]);
}

// node branch: x_node[b] = lin((ehr[b] @ node_emb)/sum(ehr[b]))
__global__ void xnode_kernel(const int* __restrict__ ehr, const float* __restrict__ emb,
                             const float* __restrict__ lw, const float* __restrict__ lb,
                             float* __restrict__ xnode) {
  int b = blockIdx.x, t = threadIdx.x;  // 128
  float acc = 0.f;
  int cnt = 0;
  const int* er = ehr + (size_t)b * kNV;
  for (int n = 0; n < kNV; n++) {
    int e = er[n];
    cnt += e;
    if (e) acc += emb[(size_t)n * kD + t];
  }
  __shared__ float pre[kD];
  pre[t] = acc / (float)cnt;
  __syncthreads();
  float o = lb[t];
  for (int d = 0; d < kD; d++) o += pre[d] * lw[t * kD + d];
  xnode[(size_t)b * kH + t] = o;
}

// out[b][o] = concat(xg[b]/cnt[b], xnode[b]) . mlp_w[o] + mlp_b[o]
__global__ void final_kernel(const float* __restrict__ xg, const int* __restrict__ cnt,
                             const float* __restrict__ xnode, const float* __restrict__ mw,
                             const float* __restrict__ mb, float* __restrict__ out) {
  int idx = blockIdx.x * blockDim.x + threadIdx.x;
  if (idx >= kB * kOut) return;
  int b = idx / kOut, o = idx % kOut;
  float inv = 1.f / (float)cnt[b];
  float acc = mb[o];
  const float* w = mw + (size_t)o * (2 * kH);
  for (int h = 0; h < kH; h++) acc += xg[b * kH + h] * inv * w[h];
  for (int h = 0; h < kH; h++) acc += xnode[b * kH + h] * w[kH + h];
  out[idx] = acc;
}

extern "C" void kernel_launch(void* const* d_in, const int* in_sizes, int n_in,
                              void* d_out, int out_size, void* d_ws, size_t ws_size,
                              hipStream_t stream) {
  const float* node_emb = (const float*)d_in[0];
  const float* edge_emb = (const float*)d_in[1];
  const float* lin_w = (const float*)d_in[2];
  const float* lin_b = (const float*)d_in[3];
  const float* alpha_w = (const float*)d_in[4];
  const float* alpha_b = (const float*)d_in[5];
  const float* beta_w = (const float*)d_in[6];
  const float* beta_b = (const float*)d_in[7];
  const float* wr_w = (const float*)d_in[8];
  const float* wr_b = (const float*)d_in[9];
  const float* conv_w = (const float*)d_in[10];
  const float* conv_b = (const float*)d_in[11];
  const float* mlp_w = (const float*)d_in[12];
  const float* mlp_b = (const float*)d_in[13];
  const int* visit_node = (const int*)d_in[14];
  const int* ehr_nodes = (const int*)d_in[15];
  const int* cat_node_ids = (const int*)d_in[16];
  const int* cat_edge_ids = (const int*)d_in[17];
  const int* edge_index = (const int*)d_in[18];
  const int* batch = (const int*)d_in[19];

  char* ws = (char*)d_ws;
  float* X = (float*)(ws);                            // 51,200,000
  float* ROWS = (float*)(ws + 51200000);              // 51,200,000
  float* PN = ROWS;                                   // alias (dead before ROWS used)
  float* LPART = (float*)(ws + 51200000 + 786432);    // 17,291,520 (alias in ROWS)
  float* ATTN = (float*)(ws + 102400000);             // 192,128
  float* BETA = (float*)(ws + 102592256);             // 3,840
  float* UC = (float*)(ws + 102596352);               // 1,032
  float* WREL = (float*)(ws + 102597632);             // 16,008
  int* OFF = (int*)(ws + 102613760);                  // 400,004
  int* CURSOR = (int*)(ws + 103014016);               // 400,000 (also DEG)
  int* SPART = (int*)(ws + 103414016);                // 2,048
  int* CSRS = (int*)(ws + 103416064);                 // 3,200,000
  float* CS0 = (float*)(ws + 106616064);              // 3,200,000
  float* CS1 = (float*)(ws + 109816064);              // 3,200,000
  float* XG = (float*)(ws + 113016064);               // 8,192
  int* CNT = (int*)(ws + 113024256);                  // 64
  float* XNODE = (float*)(ws + 113024320);            // 8,192

  pn_kernel<<<kNV, kH, 0, stream>>>(node_emb, lin_w, lin_b, PN);
  xinit_kernel<<<(kNT * 32 + 255) / 256, 256, 0, stream>>>((const float4*)PN, cat_node_ids,
                                                           (float4*)X);
  uc_kernel<<<1, 256, 0, stream>>>(wr_w, wr_b, lin_w, lin_b, UC);
  wrel_kernel<<<(kL * kNE + 255) / 256, 256, 0, stream>>>(edge_emb, UC, WREL);
  beta_kernel<<<kL * kM, 64, 0, stream>>>(visit_node, beta_w, beta_b, BETA);
  logits_kernel<<<dim3((kNV + 63) / 64, (kM + 63) / 64, kL * kKS), 256, 0, stream>>>(
      visit_node, alpha_w, LPART);
  attn_kernel<<<(kL * kB * kNV + 255) / 256, 256, 0, stream>>>(LPART, BETA, alpha_b, ATTN);

  const int* dst = edge_index + kE;
  hipMemsetAsync(CURSOR, 0, kNT * 4, stream);
  hist_kernel<<<(kE + 255) / 256, 256, 0, stream>>>(dst, CURSOR);
  scan1_kernel<<<kNB, 256, 0, stream>>>(CURSOR, OFF, SPART);
  scan2_kernel<<<1, 512, 0, stream>>>(SPART);
  scan3_kernel<<<kNB, 256, 0, stream>>>(OFF, SPART, CURSOR);
  scatter_kernel<<<(kE + 255) / 256, 256, 0, stream>>>(edge_index, cat_node_ids, cat_edge_ids,
                                                       batch, ATTN, WREL, CURSOR, CSRS, CS0, CS1);

  for (int l = 0; l < kL; l++) {
    gather_kernel<<<kNT / 8, 256, 0, stream>>>(X, CSRS, (l ? CS1 : CS0), OFF, CURSOR, ROWS);
    conv_kernel<<<kNT / 32, 256, 0, stream>>>(ROWS, conv_w + (size_t)l * kH * kD,
                                              conv_b + (size_t)l * kH, X);
  }

  hipMemsetAsync(XG, 0, kB * kH * 4 + 64, stream);
  pool_kernel<<<(kNT + 255) / 256, kH, 0, stream>>>(X, batch, XG, CNT);
  xnode_kernel<<<kB, kH, 0, stream>>>(ehr_nodes, node_emb, lin_w, lin_b, XNODE);
  final_kernel<<<2, 256, 0, stream>>>(XG, CNT, XNODE, mlp_w, mlp_b, (float*)d_out);
}

// Round 4
// 693.385 us; speedup vs baseline: 6.7801x; 1.3107x over previous
//
#include <hip/hip_runtime.h>
#include <math.h>

namespace {
constexpr int kB = 16, kV = 30, kNV = 1501, kNE = 2001, kH = 128, kD = 128,
              kL = 2, kOut = 25, kNT = 100000, kE = 800000, kM = kB * kV;
constexpr int kNB = (kNT + 255) / 256;  // 391 scan blocks
constexpr int kKS = 3;                  // split-K factor for logits
constexpr int kKCH = 501;               // ceil(1501/3)
}

// Pn[n][h] = node_emb[n] . lin_w[h] + lin_b[h]
__global__ void pn_kernel(const float* __restrict__ emb, const float* __restrict__ lw,
                          const float* __restrict__ lb, float* __restrict__ pn) {
  int n = blockIdx.x, h = threadIdx.x;
  __shared__ float row[kD];
  row[h] = emb[(size_t)n * kD + h];
  __syncthreads();
  float acc = lb[h];
#pragma unroll 8
  for (int d = 0; d < kD; d++) acc += row[d] * lw[h * kD + d];
  pn[(size_t)n * kH + h] = acc;
}

// x[i] = Pn[cat_node_ids[i]]
__global__ void xinit_kernel(const float4* __restrict__ pn4, const int* __restrict__ nid,
                             float4* __restrict__ x4) {
  int t = blockIdx.x * blockDim.x + threadIdx.x;
  if (t >= kNT * 32) return;
  int i = t >> 5, c = t & 31;
  x4[(size_t)i * 32 + c] = pn4[(size_t)nid[i] * 32 + c];
}

// node branch partials: xacc[b][h] += sum_{n in chunk, ehr[b][n]} PN[n][h]; cnte[b] += cnt
__global__ void xnode_kernel(const int* __restrict__ ehr, const float* __restrict__ pn,
                             float* __restrict__ xacc, int* __restrict__ cnte) {
  int b = blockIdx.x;   // 16
  int c = blockIdx.y;   // 12 chunks of 128 nodes
  int h = threadIdx.x;  // 128
  int n0 = c * 128;
  __shared__ int flags[128];
  int gn = n0 + h;
  flags[h] = (gn < kNV) ? ehr[(size_t)b * kNV + gn] : 0;
  __syncthreads();
  float acc = 0.f;
  int cnt = 0;
  int n1 = min(n0 + 128, kNV);
  for (int n = n0; n < n1; ++n) {
    if (flags[n - n0]) {
      acc += pn[(size_t)n * kH + h];
      cnt++;
    }
  }
  atomicAdd(&xacc[b * kH + h], acc);
  if (h == 0) atomicAdd(&cnte[b], cnt);
}

// u[l][d] = sum_h wr_w[l][h]*lin_w[h][d] ; c[l] = wr_w[l].lin_b + wr_b[l]
__global__ void uc_kernel(const float* __restrict__ wrw, const float* __restrict__ wrb,
                          const float* __restrict__ lw, const float* __restrict__ lb,
                          float* __restrict__ uc) {
  int t = threadIdx.x;  // 256
  int l = t >> 7, d = t & 127;
  float s = 0.f;
  for (int h = 0; h < kH; h++) s += wrw[l * kH + h] * lw[h * kD + d];
  uc[t] = s;
  if (t < kL) {
    float c = wrb[t];
    for (int h = 0; h < kH; h++) c += wrw[t * kH + h] * lb[h];
    uc[256 + t] = c;
  }
}

// wrel[l][r] = sigmoid(edge_emb[r] . u[l] + c[l])
__global__ void wrel_kernel(const float* __restrict__ eemb, const float* __restrict__ uc,
                            float* __restrict__ wrel) {
  int idx = blockIdx.x * blockDim.x + threadIdx.x;
  if (idx >= kL * kNE) return;
  int l = idx / kNE, r = idx % kNE;
  float z = uc[256 + l];
  const float* u = uc + l * 128;
  const float* er = eemb + (size_t)r * kD;
  for (int d = 0; d < kD; d++) z += er[d] * u[d];
  wrel[idx] = 1.f / (1.f + expf(-z));
}

// beta[l][b*V+v] = tanh(vn[b,v,:].beta_w[l] + beta_b[l]) * exp(0.01*(V-v))
__global__ void beta_kernel(const int* __restrict__ vn, const float* __restrict__ bw,
                            const float* __restrict__ bb, float* __restrict__ beta) {
  int blk = blockIdx.x;  // l*kM + r
  int l = blk / kM, r = blk % kM;
  int v = r % kV;
  int lane = threadIdx.x;
  const int* row = vn + (size_t)r * kNV;
  const float* w = bw + (size_t)l * kNV;
  float s = 0.f;
  for (int k = lane; k < kNV; k += 64) s += (float)row[k] * w[k];
  for (int off = 32; off > 0; off >>= 1) s += __shfl_down(s, off, 64);
  if (lane == 0) {
    float lam = expf(0.01f * (float)(kV - v));
    beta[blk] = tanhf(s + bb[l]) * lam;
  }
}

// Partial logits: part[z][r][n] = sum_{k in chunk ks} vn[r][k]*aw[l][n][k], z=l*kKS+ks
__global__ void logits_kernel(const int* __restrict__ vn, const float* __restrict__ aw,
                              float* __restrict__ part) {
  const int z = blockIdx.z;
  const int l = z / kKS, ks = z % kKS;
  const int rb = blockIdx.y * 64;
  const int nb = blockIdx.x * 64;
  const int tid = threadIdx.x;  // 256
  const int kbeg = ks * kKCH;
  const int kend = min(kbeg + kKCH, kNV);
  __shared__ float As[32][68];  // As[k'][m]
  __shared__ float Bs[32][68];  // Bs[k'][n]
  const float* awl = aw + (size_t)l * kNV * kNV;
  const int tx = tid & 15, ty = tid >> 4;
  const int m0 = ty * 4, n0 = tx * 4;
  float acc[4][4] = {};
  for (int k0 = kbeg; k0 < kend; k0 += 32) {
    __syncthreads();
#pragma unroll
    for (int i = 0; i < 8; ++i) {  // A: 64 m x 32 k (transposed store)
      int idx = tid + i * 256;
      int rr = idx >> 5, cc = idx & 31;
      int gr = rb + rr, gk = k0 + cc;
      As[cc][rr] = (gr < kM && gk < kend) ? (float)vn[(size_t)gr * kNV + gk] : 0.f;
    }
#pragma unroll
    for (int i = 0; i < 8; ++i) {  // B: 64 n x 32 k (transposed store)
      int idx = tid + i * 256;
      int nn = idx >> 5, cc = idx & 31;
      int gn = nb + nn, gk = k0 + cc;
      Bs[cc][nn] = (gn < kNV && gk < kend) ? awl[(size_t)gn * kNV + gk] : 0.f;
    }
    __syncthreads();
#pragma unroll
    for (int d = 0; d < 32; ++d) {
      float4 a = *(const float4*)&As[d][m0];
      float4 b4 = *(const float4*)&Bs[d][n0];
      acc[0][0] += a.x * b4.x; acc[0][1] += a.x * b4.y; acc[0][2] += a.x * b4.z; acc[0][3] += a.x * b4.w;
      acc[1][0] += a.y * b4.x; acc[1][1] += a.y * b4.y; acc[1][2] += a.y * b4.z; acc[1][3] += a.y * b4.w;
      acc[2][0] += a.z * b4.x; acc[2][1] += a.z * b4.y; acc[2][2] += a.z * b4.z; acc[2][3] += a.z * b4.w;
      acc[3][0] += a.w * b4.x; acc[3][1] += a.w * b4.y; acc[3][2] += a.w * b4.z; acc[3][3] += a.w * b4.w;
    }
  }
  float* P = part + (size_t)z * kM * kNV;
#pragma unroll
  for (int i = 0; i < 4; ++i) {
    int r = rb + m0 + i;
    if (r >= kM) break;
#pragma unroll
    for (int j = 0; j < 4; ++j) {
      int n = nb + n0 + j;
      if (n < kNV) P[(size_t)r * kNV + n] = acc[i][j];
    }
  }
}

// attn[l][b][n] = sum_v softmax_v(sum_ks part + bias) * beta[l][b][v]
__global__ void attn_kernel(const float* __restrict__ part, const float* __restrict__ beta,
                            const float* __restrict__ ab, float* __restrict__ attn) {
  int idx = blockIdx.x * blockDim.x + threadIdx.x;
  if (idx >= kL * kB * kNV) return;
  int n = idx % kNV;
  int lb_ = idx / kNV;  // l*kB + b
  int l = lb_ / kB, b = lb_ % kB;
  size_t o = (size_t)(b * kV) * kNV + n;
  const float* P0 = part + (size_t)(l * kKS + 0) * kM * kNV + o;
  const float* P1 = part + (size_t)(l * kKS + 1) * kM * kNV + o;
  const float* P2 = part + (size_t)(l * kKS + 2) * kM * kNV + o;
  float bias = ab[l * kNV + n];
  float z[kV];
  float m = -1e30f;
#pragma unroll
  for (int v = 0; v < kV; v++) {
    z[v] = P0[(size_t)v * kNV] + P1[(size_t)v * kNV] + P2[(size_t)v * kNV] + bias;
    m = fmaxf(m, z[v]);
  }
  float s = 0.f, num = 0.f;
  const float* bet = beta + lb_ * kV;
#pragma unroll
  for (int v = 0; v < kV; v++) {
    float e = expf(z[v] - m);
    s += e;
    num += e * bet[v];
  }
  attn[idx] = num / s;
}

// ---- CSR build ----
__global__ void hist_kernel(const int* __restrict__ dst, int* __restrict__ deg) {
  int e = blockIdx.x * blockDim.x + threadIdx.x;
  if (e >= kE) return;
  atomicAdd(&deg[dst[e]], 1);
}

__global__ void scan1_kernel(const int* __restrict__ deg, int* __restrict__ off,
                             int* __restrict__ part) {
  int t = threadIdx.x, i = blockIdx.x * 256 + t;
  int v = (i < kNT) ? deg[i] : 0;
  __shared__ int sm[256];
  sm[t] = v;
  __syncthreads();
  for (int o = 1; o < 256; o <<= 1) {
    int x = (t >= o) ? sm[t - o] : 0;
    __syncthreads();
    sm[t] += x;
    __syncthreads();
  }
  if (i < kNT) off[i] = sm[t] - v;
  if (t == 255) part[blockIdx.x] = sm[255];
}

__global__ void scan2_kernel(int* __restrict__ part) {
  int t = threadIdx.x;  // 512
  int v = (t < kNB) ? part[t] : 0;
  __shared__ int sm[512];
  sm[t] = v;
  __syncthreads();
  for (int o = 1; o < 512; o <<= 1) {
    int x = (t >= o) ? sm[t - o] : 0;
    __syncthreads();
    sm[t] += x;
    __syncthreads();
  }
  if (t < kNB) part[t] = sm[t] - v;
}

__global__ void scan3_kernel(int* __restrict__ off, const int* __restrict__ part,
                             int* __restrict__ cursor) {
  int i = blockIdx.x * 256 + threadIdx.x;
  if (i >= kNT) return;
  int o = off[i] + part[blockIdx.x];
  off[i] = o;
  cursor[i] = o;
}

// scatter edges into CSR slots; precompute per-edge scalars for both layers
__global__ void scatter_kernel(const int* __restrict__ ei, const int* __restrict__ nid,
                               const int* __restrict__ eid, const int* __restrict__ batch,
                               const float* __restrict__ attn, const float* __restrict__ wrel,
                               int* __restrict__ cursor, int* __restrict__ csrc,
                               float* __restrict__ cs0, float* __restrict__ cs1) {
  int e = blockIdx.x * blockDim.x + threadIdx.x;
  if (e >= kE) return;
  int s = ei[e], d = ei[kE + e];
  int b = batch[s], n = nid[s], r = eid[e];
  float a0 = attn[(size_t)b * kNV + n];
  float a1 = attn[(size_t)kB * kNV + b * kNV + n];
  float w0 = wrel[r], w1 = wrel[kNE + r];
  int pos = atomicAdd(&cursor[d], 1);
  csrc[pos] = s;
  cs0[pos] = a0 * w0;
  cs1[pos] = a1 * w1;
}

// rows[n] = x[n] + sum_{edges->n} relu(x[src]*scal)
// 2 nodes per wave, float4 per lane (32 lanes/row), 32-edge register prefetch.
__global__ void gather_kernel(const float* __restrict__ x, const int* __restrict__ csrc,
                              const float* __restrict__ cscal, const int* __restrict__ off,
                              const int* __restrict__ endv, float* __restrict__ rows) {
  int wid = (blockIdx.x * blockDim.x + threadIdx.x) >> 6;
  int lane = threadIdx.x & 63;
  int sub = lane >> 5, sl = lane & 31;
  int node = wid * 2 + sub;
  if (node >= kNT) return;
  const float4* x4 = (const float4*)x;
  float4 acc = x4[(size_t)node * 32 + sl];
  int j0 = off[node], j1 = endv[node];
  for (int base = j0; base < j1; base += 32) {
    int n = j1 - base;
    if (n > 32) n = 32;
    int sidx = 0;
    float ssc = 0.f;
    if (sl < n) {
      sidx = csrc[base + sl];
      ssc = cscal[base + sl];
    }
    for (int t = 0; t < n; ++t) {
      int s = __shfl(sidx, sub * 32 + t, 64);
      float sc = __shfl(ssc, sub * 32 + t, 64);
      float4 xv = x4[(size_t)s * 32 + sl];
      acc.x += fmaxf(xv.x * sc, 0.f);
      acc.y += fmaxf(xv.y * sc, 0.f);
      acc.z += fmaxf(xv.z * sc, 0.f);
      acc.w += fmaxf(xv.w * sc, 0.f);
    }
  }
  ((float4*)rows)[(size_t)node * 32 + sl] = acc;
}

// x_out[n][h] = relu(rows[n] . w[h] + bias[h]); 32 nodes/block, K-chunks of 32, 4x4/thread
__global__ void conv_kernel(const float* __restrict__ rows, const float* __restrict__ w,
                            const float* __restrict__ bias, float* __restrict__ xout) {
  const int nb = blockIdx.x * 32;
  const int tid = threadIdx.x;  // 256
  __shared__ float rT[128][36];   // rT[d][n]
  __shared__ float Wc[32][132];   // Wc[d'][h]
  float4 acc0 = {0, 0, 0, 0}, acc1 = {0, 0, 0, 0}, acc2 = {0, 0, 0, 0}, acc3 = {0, 0, 0, 0};
#pragma unroll
  for (int i = 0; i < 4; ++i) {
    int fi = tid + i * 256;
    int n = fi >> 5, d0 = (fi & 31) * 4;
    float4 v = *(const float4*)(rows + (size_t)(nb + n) * kH + d0);
    rT[d0 + 0][n] = v.x;
    rT[d0 + 1][n] = v.y;
    rT[d0 + 2][n] = v.z;
    rT[d0 + 3][n] = v.w;
  }
  const int h0 = (tid & 31) * 4;
  const int n0 = (tid >> 5) * 4;
  for (int kc = 0; kc < 4; ++kc) {
    __syncthreads();
#pragma unroll
    for (int i = 0; i < 4; ++i) {
      int fi = tid + i * 256;
      int h = fi >> 3, c0 = (fi & 7) * 4;
      float4 v = *(const float4*)(w + (size_t)h * kD + kc * 32 + c0);
      Wc[c0 + 0][h] = v.x;
      Wc[c0 + 1][h] = v.y;
      Wc[c0 + 2][h] = v.z;
      Wc[c0 + 3][h] = v.w;
    }
    __syncthreads();
#pragma unroll
    for (int d = 0; d < 32; ++d) {
      float4 a = *(const float4*)&rT[kc * 32 + d][n0];
      float4 b4 = *(const float4*)&Wc[d][h0];
      acc0.x += a.x * b4.x; acc0.y += a.x * b4.y; acc0.z += a.x * b4.z; acc0.w += a.x * b4.w;
      acc1.x += a.y * b4.x; acc1.y += a.y * b4.y; acc1.z += a.y * b4.z; acc1.w += a.y * b4.w;
      acc2.x += a.z * b4.x; acc2.y += a.z * b4.y; acc2.z += a.z * b4.z; acc2.w += a.z * b4.w;
      acc3.x += a.w * b4.x; acc3.y += a.w * b4.y; acc3.z += a.w * b4.z; acc3.w += a.w * b4.w;
    }
  }
  float4 bv = *(const float4*)(bias + h0);
  float4 o0, o1, o2, o3;
  o0.x = fmaxf(acc0.x + bv.x, 0.f); o0.y = fmaxf(acc0.y + bv.y, 0.f);
  o0.z = fmaxf(acc0.z + bv.z, 0.f); o0.w = fmaxf(acc0.w + bv.w, 0.f);
  o1.x = fmaxf(acc1.x + bv.x, 0.f); o1.y = fmaxf(acc1.y + bv.y, 0.f);
  o1.z = fmaxf(acc1.z + bv.z, 0.f); o1.w = fmaxf(acc1.w + bv.w, 0.f);
  o2.x = fmaxf(acc2.x + bv.x, 0.f); o2.y = fmaxf(acc2.y + bv.y, 0.f);
  o2.z = fmaxf(acc2.z + bv.z, 0.f); o2.w = fmaxf(acc2.w + bv.w, 0.f);
  o3.x = fmaxf(acc3.x + bv.x, 0.f); o3.y = fmaxf(acc3.y + bv.y, 0.f);
  o3.z = fmaxf(acc3.z + bv.z, 0.f); o3.w = fmaxf(acc3.w + bv.w, 0.f);
  *(float4*)(xout + (size_t)(nb + n0 + 0) * kH + h0) = o0;
  *(float4*)(xout + (size_t)(nb + n0 + 1) * kH + h0) = o1;
  *(float4*)(xout + (size_t)(nb + n0 + 2) * kH + h0) = o2;
  *(float4*)(xout + (size_t)(nb + n0 + 3) * kH + h0) = o3;
}

// mean-pool: register accumulation with flush-on-batch-change (correct for any batch array)
__global__ void pool_kernel(const float* __restrict__ x, const int* __restrict__ batch,
                            float* __restrict__ xg, int* __restrict__ cnt) {
  int h = threadIdx.x;  // 128
  int start = blockIdx.x * 256;
  int end = start + 256;
  if (end > kNT) end = kNT;
  int cur = batch[start];
  float acc = 0.f;
  int c = 0;
  for (int i = start; i < end; i++) {
    int bb = batch[i];
    if (bb != cur) {
      atomicAdd(&xg[cur * kH + h], acc);
      if (h == 0) atomicAdd(&cnt[cur], c);
      acc = 0.f;
      c = 0;
      cur = bb;
    }
    acc += x[(size_t)i * kH + h];
    c++;
  }
  atomicAdd(&xg[cur * kH + h], acc);
  if (h == 0) atomicAdd(&cnt[cur], c);
}

// out[b][o] = concat(xg[b]/cnt[b], xacc[b]/cnte[b]) . mlp_w[o] + mlp_b[o]
__global__ void final_kernel(const float* __restrict__ xg, const int* __restrict__ cnt,
                             const float* __restrict__ xacc, const int* __restrict__ cnte,
                             const float* __restrict__ mw, const float* __restrict__ mb,
                             float* __restrict__ out) {
  int idx = blockIdx.x * blockDim.x + threadIdx.x;
  if (idx >= kB * kOut) return;
  int b = idx / kOut, o = idx % kOut;
  float invg = 1.f / (float)cnt[b];
  float invn = 1.f / (float)cnte[b];
  float acc = mb[o];
  const float* w = mw + (size_t)o * (2 * kH);
  for (int h = 0; h < kH; h++) acc += xg[b * kH + h] * invg * w[h];
  for (int h = 0; h < kH; h++) acc += xacc[b * kH + h] * invn * w[kH + h];
  out[idx] = acc;
}

extern "C" void kernel_launch(void* const* d_in, const int* in_sizes, int n_in,
                              void* d_out, int out_size, void* d_ws, size_t ws_size,
                              hipStream_t stream) {
  const float* node_emb = (const float*)d_in[0];
  const float* edge_emb = (const float*)d_in[1];
  const float* lin_w = (const float*)d_in[2];
  const float* lin_b = (const float*)d_in[3];
  const float* alpha_w = (const float*)d_in[4];
  const float* alpha_b = (const float*)d_in[5];
  const float* beta_w = (const float*)d_in[6];
  const float* beta_b = (const float*)d_in[7];
  const float* wr_w = (const float*)d_in[8];
  const float* wr_b = (const float*)d_in[9];
  const float* conv_w = (const float*)d_in[10];
  const float* conv_b = (const float*)d_in[11];
  const float* mlp_w = (const float*)d_in[12];
  const float* mlp_b = (const float*)d_in[13];
  const int* visit_node = (const int*)d_in[14];
  const int* ehr_nodes = (const int*)d_in[15];
  const int* cat_node_ids = (const int*)d_in[16];
  const int* cat_edge_ids = (const int*)d_in[17];
  const int* edge_index = (const int*)d_in[18];
  const int* batch = (const int*)d_in[19];

  char* ws = (char*)d_ws;
  float* X = (float*)(ws);                            // 51,200,000
  float* ROWS = (float*)(ws + 51200000);              // 51,200,000
  float* PN = ROWS;                                   // alias (dead before ROWS used)
  float* LPART = (float*)(ws + 51200000 + 786432);    // 17,291,520 (alias in ROWS)
  float* ATTN = (float*)(ws + 102400000);             // 192,128
  float* BETA = (float*)(ws + 102592256);             // 3,840
  float* UC = (float*)(ws + 102596352);               // 1,032
  float* WREL = (float*)(ws + 102597632);             // 16,008
  int* OFF = (int*)(ws + 102613760);                  // 400,004
  int* CURSOR = (int*)(ws + 103014016);               // 400,000 (also DEG)
  int* SPART = (int*)(ws + 103414016);                // 2,048
  int* CSRS = (int*)(ws + 103416064);                 // 3,200,000
  float* CS0 = (float*)(ws + 106616064);              // 3,200,000
  float* CS1 = (float*)(ws + 109816064);              // 3,200,000
  float* XG = (float*)(ws + 113016064);               // 8,192
  int* CNT = (int*)(ws + 113024256);                  // 64
  float* XNACC = (float*)(ws + 113024320);            // 8,192
  int* CNTE = (int*)(ws + 113032512);                 // 64

  pn_kernel<<<kNV, kH, 0, stream>>>(node_emb, lin_w, lin_b, PN);
  xinit_kernel<<<(kNT * 32 + 255) / 256, 256, 0, stream>>>((const float4*)PN, cat_node_ids,
                                                           (float4*)X);
  // zero XG + CNT + XNACC + CNTE (contiguous 16,512 B)
  hipMemsetAsync(XG, 0, 16512, stream);
  xnode_kernel<<<dim3(kB, 12), kH, 0, stream>>>(ehr_nodes, PN, XNACC, CNTE);
  uc_kernel<<<1, 256, 0, stream>>>(wr_w, wr_b, lin_w, lin_b, UC);
  wrel_kernel<<<(kL * kNE + 255) / 256, 256, 0, stream>>>(edge_emb, UC, WREL);
  beta_kernel<<<kL * kM, 64, 0, stream>>>(visit_node, beta_w, beta_b, BETA);
  logits_kernel<<<dim3((kNV + 63) / 64, (kM + 63) / 64, kL * kKS), 256, 0, stream>>>(
      visit_node, alpha_w, LPART);
  attn_kernel<<<(kL * kB * kNV + 255) / 256, 256, 0, stream>>>(LPART, BETA, alpha_b, ATTN);

  const int* dst = edge_index + kE;
  hipMemsetAsync(CURSOR, 0, kNT * 4, stream);
  hist_kernel<<<(kE + 255) / 256, 256, 0, stream>>>(dst, CURSOR);
  scan1_kernel<<<kNB, 256, 0, stream>>>(CURSOR, OFF, SPART);
  scan2_kernel<<<1, 512, 0, stream>>>(SPART);
  scan3_kernel<<<kNB, 256, 0, stream>>>(OFF, SPART, CURSOR);
  scatter_kernel<<<(kE + 255) / 256, 256, 0, stream>>>(edge_index, cat_node_ids, cat_edge_ids,
                                                       batch, ATTN, WREL, CURSOR, CSRS, CS0, CS1);

  for (int l = 0; l < kL; l++) {
    gather_kernel<<<kNT / 8, 256, 0, stream>>>(X, CSRS, (l ? CS1 : CS0), OFF, CURSOR, ROWS);
    conv_kernel<<<kNT / 32, 256, 0, stream>>>(ROWS, conv_w + (size_t)l * kH * kD,
                                              conv_b + (size_t)l * kH, X);
  }

  pool_kernel<<<(kNT + 255) / 256, kH, 0, stream>>>(X, batch, XG, CNT);
  final_kernel<<<2, 256, 0, stream>>>(XG, CNT, XNACC, CNTE, mlp_w, mlp_b, (float*)d_out);
}